// Round 5
// baseline (1774.659 us; speedup 1.0000x reference)
//
#include <hip/hip_runtime.h>
#include <hip/hip_bf16.h>

#define Bc 4
#define Tc 256
#define Nc 4096
#define Kc 64
#define DEGc 4
#define Lc (Tc - 1)
#define NNZc (Bc * Nc * DEGc)
#define NPB 8                         // blocks (slices) per batch
#define TPB 512                       // threads per scan block
#define TPB_EM 256
#define NODES_PER (Nc / NPB)          // 512 -> one node per thread
#define INV_N (1.0f / 4096.0f)

typedef float f32x4 __attribute__((ext_vector_type(4)));

__device__ __forceinline__ float cohLoadF(const float* p) {
  return __hip_atomic_load((float*)p, __ATOMIC_RELAXED, __HIP_MEMORY_SCOPE_AGENT);
}
// 16B store that bypasses the (non-coherent) per-XCD L2. ext_vector -> VGPR quad.
__device__ __forceinline__ void cohStore4(float* p, f32x4 v) {
  asm volatile("global_store_dwordx4 %0, %1, off sc0 sc1" :: "v"(p), "v"(v) : "memory");
}

template <int NT>
__device__ __forceinline__ float blockSumT(float v, volatile float* red) {
#pragma unroll
  for (int o = 1; o < 64; o <<= 1) v += __shfl_xor(v, o, 64);
  __syncthreads();
  if ((threadIdx.x & 63) == 0) red[threadIdx.x >> 6] = v;
  __syncthreads();
  float s = 0.f;
#pragma unroll
  for (int k = 0; k < NT / 64; ++k) s += red[k];
  return s;
}
template <int NT>
__device__ __forceinline__ float blockMaxT(float v, volatile float* red) {
#pragma unroll
  for (int o = 1; o < 64; o <<= 1) v = fmaxf(v, __shfl_xor(v, o, 64));
  __syncthreads();
  if ((threadIdx.x & 63) == 0) red[threadIdx.x >> 6] = v;
  __syncthreads();
  float m = -INFINITY;
#pragma unroll
  for (int k = 0; k < NT / 64; ++k) m = fmaxf(m, red[k]);
  return m;
}

// emexp[r][n] = softmax(obs[r,:] @ W)[n]  (EXP form), one block per row r
__global__ __launch_bounds__(TPB_EM) void em_kernel(const float* __restrict__ obs,
                                                    const float* __restrict__ W,
                                                    float* __restrict__ emexp) {
  const int r = blockIdx.x, tid = threadIdx.x;
  __shared__ float o[Kc];
  __shared__ float red[8];
  if (tid < Kc) o[tid] = obs[(size_t)r * Kc + tid];
  __syncthreads();
  float4 acc[4];
#pragma unroll
  for (int gI = 0; gI < 4; ++gI) acc[gI] = make_float4(0.f, 0.f, 0.f, 0.f);
  const float4* W4 = (const float4*)W;
  for (int k = 0; k < Kc; ++k) {
    const float ov = o[k];
    const float4* wr = W4 + (size_t)k * (Nc / 4);
#pragma unroll
    for (int gI = 0; gI < 4; ++gI) {
      float4 w = wr[gI * 256 + tid];
      acc[gI].x = fmaf(ov, w.x, acc[gI].x);
      acc[gI].y = fmaf(ov, w.y, acc[gI].y);
      acc[gI].z = fmaf(ov, w.z, acc[gI].z);
      acc[gI].w = fmaf(ov, w.w, acc[gI].w);
    }
  }
  float m = -INFINITY;
#pragma unroll
  for (int gI = 0; gI < 4; ++gI)
    m = fmaxf(m, fmaxf(fmaxf(acc[gI].x, acc[gI].y), fmaxf(acc[gI].z, acc[gI].w)));
  m = blockMaxT<TPB_EM>(m, red);
  float s = 0.f;
#pragma unroll
  for (int gI = 0; gI < 4; ++gI)
    s += __expf(acc[gI].x - m) + __expf(acc[gI].y - m) + __expf(acc[gI].z - m) + __expf(acc[gI].w - m);
  s = blockSumT<TPB_EM>(s, red);
  const float lse = m + __logf(s);
  float4* em4 = (float4*)emexp;
#pragma unroll
  for (int gI = 0; gI < 4; ++gI) {
    float4 w = acc[gI];
    w.x = __expf(w.x - lse); w.y = __expf(w.y - lse);
    w.z = __expf(w.z - lse); w.w = __expf(w.w - lse);
    em4[(size_t)r * (Nc / 4) + gI * 256 + tid] = w;
  }
}

__device__ __forceinline__ void publish(unsigned long long* slot, unsigned t, float sp) {
  union { float f; unsigned u; } c; c.f = sp;
  unsigned long long v = ((unsigned long long)c.u << 32) | (unsigned long long)t;
  __hip_atomic_store(slot, v, __ATOMIC_RELAXED, __HIP_MEMORY_SCOPE_AGENT);
}
// Poll all 8 slice flags of this parity until value >= t; returns Sum(S-partials).
__device__ __forceinline__ float pollFlags(unsigned long long* fb, int parity, unsigned t) {
  unsigned long long* base = fb + parity * 8;
  for (;;) {
    unsigned long long v[8];
#pragma unroll
    for (int k = 0; k < 8; ++k)
      v[k] = __hip_atomic_load(&base[k], __ATOMIC_RELAXED, __HIP_MEMORY_SCOPE_AGENT);
    bool ok = true;
    float s = 0.f;
#pragma unroll
    for (int k = 0; k < 8; ++k) {
      ok &= ((unsigned)(v[k] & 0xffffffffull) >= t);
      union { unsigned u; float f; } c; c.u = (unsigned)(v[k] >> 32);
      s += c.f;
    }
    if (ok) return s;
  }
}

// grid = B*NPB blocks; thread tid of (b, sl) owns node sl*512+tid and its 4
// out-edges. Linear-space scaled forward recurrence; per-round exchange:
// LDS scatter -> vectorized coherent writeout -> flag{t, S-partial} publish ->
// poll -> dense gather. Flags are monotone (no reset); runs only t* rounds.
__global__ __launch_bounds__(TPB) void scan_kernel(
    const int* __restrict__ duration,
    const int* __restrict__ tidx,       // (L, NNZ, 3) int32 (b, src, tgt)
    const float* __restrict__ tlv,      // (L, NNZ)
    const float* __restrict__ emexp,    // (B*T, N) softmax (EXP form)
    float* __restrict__ part,           // [2][B][NPB][N]
    unsigned long long* __restrict__ flags,  // [B][2][8]
    float* __restrict__ out) {
  const int g = blockIdx.x;
  const int b = g / NPB, sl = g % NPB;
  const int tid = threadIdx.x;
  __shared__ float red[TPB / 64];
  __shared__ float lsb[Nc];
  __shared__ float sprev_sh;

  const int node = sl * NODES_PER + tid;
  const size_t ebase = (size_t)b * (Nc * DEGc) + (size_t)node * DEGc;
  unsigned long long* fb = flags + (size_t)b * 16;
  const int tstar = duration[b] - 1;   // rounds to run

  // zero LDS scatter buffer
#pragma unroll
  for (int i = 0; i < Nc / TPB; ++i) lsb[i * TPB + tid] = 0.f;

  // ---- t=0 state: a~_0 = softmax(row0)/N ; S_0 partial ----
  float v = emexp[((size_t)b * Tc) * Nc + node] * INV_N;
  float Spart = blockSumT<TPB>(v, red);  // also fences lsb zeroing
  float inv_sprev = 1.0f;                // round-1 scale (S_{-1} := 1)
  float acc = 0.f;                       // sl0/tid0: sum of log S_tau, tau<=t*-2

  // prologue prefetch: edges row 0 (round 1), em row 1
  int4 c0, c1, c2; float4 cl; float em_cur;
  {
    const int4* ip = (const int4*)tidx + ((ebase * 3) >> 2);
    c0 = ip[0]; c1 = ip[1]; c2 = ip[2];
    cl = ((const float4*)tlv)[ebase >> 2];
    em_cur = emexp[((size_t)b * Tc + 1) * Nc + node];
  }

  for (int t = 1; t <= tstar; ++t) {
    // ---- A: scatter a~_{t-1}[node] * exp(lv) into LDS ----
    const float a = v * inv_sprev;
    atomicAdd(&lsb[c0.z], a * __expf(cl.x));
    atomicAdd(&lsb[c1.y], a * __expf(cl.y));
    atomicAdd(&lsb[c2.x], a * __expf(cl.z));
    atomicAdd(&lsb[c2.w], a * __expf(cl.w));
    __syncthreads();

    // ---- writeout: 32B per thread, vectorized; re-zero LDS behind the read ----
    float* pp = part + (((size_t)(t & 1) * Bc + b) * NPB + sl) * Nc;
    {
      f32x4 w0 = *(const f32x4*)&lsb[tid * 8];
      f32x4 w1 = *(const f32x4*)&lsb[tid * 8 + 4];
      *(f32x4*)&lsb[tid * 8] = (f32x4)0.0f;
      *(f32x4*)&lsb[tid * 8 + 4] = (f32x4)0.0f;
      cohStore4(&pp[tid * 8], w0);
      cohStore4(&pp[tid * 8 + 4], w1);
    }
    __syncthreads();   // each wave drains its stores (vmcnt 0) before barrier

    // ---- publish flag {t, S_{t-1} partial} ----
    if (tid == 0) {
      asm volatile("s_waitcnt vmcnt(0)" ::: "memory");  // belt & braces
      publish(&fb[(t & 1) * 8 + sl], (unsigned)t, Spart);
    }

    // ---- prefetch next round (after drain barrier: off the critical chain) ----
    int4 m0 = c0, m1 = c1, m2 = c2; float4 ml = cl; float em_nxt = em_cur;
    if (t < tstar) {
      const size_t e = (size_t)t * NNZc + ebase;
      const int4* ip = (const int4*)tidx + ((e * 3) >> 2);
      m0 = ip[0]; m1 = ip[1]; m2 = ip[2];
      ml = ((const float4*)tlv)[e >> 2];
      em_nxt = emexp[((size_t)b * Tc + t + 1) * Nc + node];
    }

    // ---- poll: sync + S_{t-1} in one trip ----
    if (tid == 0) {
      float sp = pollFlags(fb, t & 1, (unsigned)t);
      sprev_sh = sp;
      if (sl == 0 && t <= tstar - 1) acc += __logf(sp);
    }
    __syncthreads();
    const float sprev = sprev_sh;        // full S_{t-1}

    // ---- gather NPB partials, v_t = sum * e_t ----
    const float* pbase = part + ((size_t)(t & 1) * Bc + b) * NPB * Nc;
    float pk[NPB];
#pragma unroll
    for (int k = 0; k < NPB; ++k) pk[k] = cohLoadF(&pbase[(size_t)k * Nc + node]);
    float sv = 0.f;
#pragma unroll
    for (int k = 0; k < NPB; ++k) sv += pk[k];
    v = sv * em_cur;                     // unscaled v_t
    Spart = blockSumT<TPB>(v, red);      // S_t partial
    inv_sprev = __frcp_rn(sprev);        // a~_t = v_t / S_{t-1} next round

    c0 = m0; c1 = m1; c2 = m2; cl = ml; em_cur = em_nxt;
  }

  // ---- final exchange: S_{t*} ----
  __syncthreads();
  if (tid == 0) {
    publish(&fb[((tstar + 1) & 1) * 8 + sl], (unsigned)(tstar + 1), Spart);
    if (sl == 0) {
      float sf = pollFlags(fb, (tstar + 1) & 1, (unsigned)(tstar + 1));
      out[b] = acc + __logf(sf);   // log S_{t*} + sum_{tau<=t*-2} log S_tau
    }
  }
}

extern "C" void kernel_launch(void* const* d_in, const int* in_sizes, int n_in,
                              void* d_out, int out_size, void* d_ws, size_t ws_size,
                              hipStream_t stream) {
  const float* obs = (const float*)d_in[0];
  const float* W = (const float*)d_in[1];
  const int* duration = (const int*)d_in[2];
  const int* tidx = (const int*)d_in[3];
  const float* tlv = (const float*)d_in[4];
  float* out = (float*)d_out;

  float* emexp = (float*)d_ws;                                   // B*T*N f32 (16MB)
  float* part = emexp + (size_t)Bc * Tc * Nc;                    // 2*B*NPB*N f32 (1MB)
  unsigned long long* flags = (unsigned long long*)(part + (size_t)2 * Bc * NPB * Nc);

  (void)hipMemsetAsync(flags, 0, Bc * 16 * sizeof(unsigned long long), stream);

  em_kernel<<<dim3(Bc * Tc), dim3(TPB_EM), 0, stream>>>(obs, W, emexp);
  scan_kernel<<<dim3(Bc * NPB), dim3(TPB), 0, stream>>>(duration, tidx, tlv, emexp,
                                                        part, flags, out);
}